// Round 14
// baseline (159.521 us; speedup 1.0000x reference)
//
#include <hip/hip_runtime.h>
#include <math.h>

// Problem constants
#define NB   16
#define NC   64
#define HWs  4096
#define NPS  1024
#define LOG2E 1.44269504088896341f

// ws layout in ushort (bf16 bit patterns)
static constexpr size_t PHI_OFF = (size_t)NB * HWs * 8;            // theta: [b][4096][8]
static constexpr size_t GT_OFF  = PHI_OFF + (size_t)NB * NPS * 8;  // phi:   [b][1024][8]
// gT: [b][32][1024]; total 1,179,648 ushorts = 2.25 MB
static constexpr size_t PROBE_OFF = (size_t)16 * 1024 * 1024;      // 32 MB scratch (ushort units)

typedef short s16x8 __attribute__((ext_vector_type(8)));
typedef float f32x4 __attribute__((ext_vector_type(4)));

#define LD8G(p) (*(const s16x8*)(p))
#define SB()    __builtin_amdgcn_sched_barrier(0)

__device__ inline unsigned short f2bf(float f) {
    unsigned int u = __float_as_uint(f);
    u += 0x7fffu + ((u >> 16) & 1u);          // RNE
    return (unsigned short)(u >> 16);
}
__device__ inline unsigned int pk2(float a, float b) {
    unsigned int ua = __float_as_uint(a); ua += 0x7fffu + ((ua >> 16) & 1u);
    unsigned int ub = __float_as_uint(b); ub += 0x7fffu + ((ub >> 16) & 1u);
    return (ua >> 16) | (ub & 0xffff0000u);
}

// ---------------------------------------------------------------------------
// Kernel 1 (v5): FINAL. Round-18 finding: the probe showed proj is ~8-10 us
// (probe marginal cost 15.1 us at 2x grid), near its 32-MB-read memory
// floor. The "proj ~28" belief was a budget-model error (fixed overhead is
// ~70 us: fill 44-46 + ~25 secondary memsets/gaps). v6/v7 "fixes" were real
// regressions of an already-fast kernel. proj is DONE.
// ---------------------------------------------------------------------------
__global__ __launch_bounds__(256) __attribute__((amdgpu_waves_per_eu(8, 8)))
void k_proj(
    const float* __restrict__ x, const float* __restrict__ Wt,
    const float* __restrict__ Wp, const float* __restrict__ Wg,
    unsigned short* __restrict__ ws)
{
    __shared__ float xs[64 * 64];             // 16 KB

    unsigned short* theta = ws;
    unsigned short* phi   = ws + PHI_OFF;
    unsigned short* gT    = ws + GT_OFF;

    const int tid  = threadIdx.x;
    const int blk  = blockIdx.x;
    const int b    = blk >> 7;
    const int rp   = (blk >> 2) & 31;         // image rows {2rp, 2rp+1}
    const int half = (blk >> 1) & 1;          // block-uniform -> SGPR
    const int csub = blk & 1;                 // column half (32 cols)
    const int col0 = csub * 32;

    const float* xsrc = x + (size_t)b * NC * HWs + rp * 128;
#pragma unroll
    for (int i = 0; i < 4; ++i) {
        const int idx  = i * 256 + tid;       // 0..1023 float4 slots
        const int ci   = idx >> 4;
        const int slot = idx & 15;
        const int r    = slot >> 3;
        const int c4   = slot & 7;
        float4 v = *(const float4*)(xsrc + (size_t)ci * HWs + r * 64 + col0 + c4 * 4);
        *(float4*)(xs + ci * 64 + r * 32 + c4 * 4) = v;
    }
    __syncthreads();

    const int pxl = tid & 63;                 // r = pxl>>5, c = pxl&31
    const int r   = pxl >> 5;
    const int c   = pxl & 31;
    const int grp = __builtin_amdgcn_readfirstlane(tid >> 6);   // 0..3, SGPR

    float a2[2], ag4[4];
#pragma unroll
    for (int j = 0; j < 2; ++j) a2[j] = 0.f;
#pragma unroll
    for (int j = 0; j < 4; ++j) ag4[j] = 0.f;

    const float* W8 = (half ? Wp : Wt) + grp * 2 * NC;           // scalar base
    const float* WG = Wg + (half * 16 + grp * 4) * NC;           // scalar base

#pragma unroll 8
    for (int ci = 0; ci < NC; ++ci) {
        const float xv = xs[ci * 64 + pxl];   // 2-way bank alias: free
#pragma unroll
        for (int j = 0; j < 2; ++j) a2[j] += W8[j * NC + ci] * xv;    // s_load
#pragma unroll
        for (int j = 0; j < 4; ++j) ag4[j] += WG[j * NC + ci] * xv;   // s_load
    }

    if (half == 0) {
        const int q = (2 * rp + r) * 64 + col0 + c;
        *(unsigned int*)(theta + ((size_t)b * HWs + q) * 8 + grp * 2) =
            pk2(a2[0] * LOG2E, a2[1] * LOG2E);
    } else {
#pragma unroll
        for (int j = 0; j < 2; ++j) {
            float v = a2[j];
            v = fmaxf(v, __shfl_xor(v, 32));
            v = fmaxf(v, __shfl_xor(v, 1));
            a2[j] = v;
        }
    }

#pragma unroll
    for (int j = 0; j < 4; ++j) {
        float v = ag4[j];
        v = fmaxf(v, __shfl_xor(v, 32));
        v = fmaxf(v, __shfl_xor(v, 1));
        ag4[j] = v;
    }

    if (r == 0 && (c & 1) == 0) {
        const int ps = rp * 32 + csub * 16 + (c >> 1);
        if (half == 1) {
            *(unsigned int*)(phi + ((size_t)b * NPS + ps) * 8 + grp * 2) =
                pk2(a2[0], a2[1]);
        }
#pragma unroll
        for (int j = 0; j < 4; ++j) {
            const int ch = half * 16 + grp * 4 + j;
            gT[((size_t)b * 32 + ch) * NPS + ps] = f2bf(ag4[j]);
        }
    }
}

// ---------------------------------------------------------------------------
// Kernel 2 (v11, templated for instrumentation). Round-18: attn (~34 us vs
// ~6-10 us floor) is the ONLY remaining controllable cost, and its current
// stage+stagger form has NEVER had counters (below the fill cutoff since
// v11 landed). PROBE instantiation: 2x grid (blk & 1023 — each tile
// computed twice, identical values), output to ws+32MB scratch; lands top-1
// (~68 us) with full counters for EXACTLY this code. Real instantiation is
// byte-identical math, runs last, overwrites every out element.
// Decision tree (next round): VALU>=60 -> shrink softmax VALU | Occ~33 +
// VALU~35 + Mfma<10 -> batch barriers + deepen prefetch | bank-conflict
// >>1M -> stage swizzle wrong | FETCH >> expected -> stagger ineffective.
// ---------------------------------------------------------------------------
template<bool PROBE>
__global__ __launch_bounds__(256) __attribute__((amdgpu_waves_per_eu(4, 4)))
void k_attn_t(
    const float* __restrict__ x, const float* __restrict__ Wo,
    const float* __restrict__ gamma_p, const unsigned short* __restrict__ ws,
    float* __restrict__ out)
{
    __shared__ __align__(16) unsigned char smem[26624];

    const int tid  = threadIdx.x;
    const int wave = __builtin_amdgcn_readfirstlane(tid >> 6);
    const int lane = tid & 63;
    const int quad = lane >> 4, lr = lane & 15;
    const int blk  = PROBE ? (blockIdx.x & 1023) : blockIdx.x;
    const int b    = blk >> 6;
    const int q0   = (blk & 63) * 64;
    const int stoff = blk & 15;               // tile stagger (block-uniform)

    const unsigned short* th = ws + (size_t)b * HWs * 8;
    const unsigned short* ph = ws + PHI_OFF + (size_t)b * NPS * 8;
    const unsigned short* gp = ws + GT_OFF + (size_t)b * 32 * NPS;
    unsigned short* Pw  = (unsigned short*)smem + wave * 2304;     // 2 bufs x [16 q][72 s]
    unsigned short* stg = (unsigned short*)(smem + 18432);         // 2 bufs x [32 ch][64 s]

    const int sch   = tid >> 3;
    const int spart = tid & 7;
    const int swz   = spart ^ (sch & 7);
    const int voff_gc = sch * (NPS * 2) + spart * 16;   // byte voffset into gT slab

    const s16x8 zf = {0, 0, 0, 0, 0, 0, 0, 0};
    const f32x4 zc = {0.f, 0.f, 0.f, 0.f};

    // theta A-fragment: A[m=q=lr][k=quad*8+j], real k<8 in quad 0
    const s16x8 thA = (quad == 0) ? LD8G(th + (size_t)(q0 + wave * 16 + lr) * 8) : zf;

    f32x4 O[2];
    f32x4 l4;
#pragma unroll
    for (int r = 0; r < 4; ++r) { O[0][r] = 0.f; O[1][r] = 0.f; l4[r] = 0.f; }

    const int voff_ph0 = (0 * 16 + lr) * 16;
    const int voff_ph1 = (1 * 16 + lr) * 16;
    const int voff_ph2 = (2 * 16 + lr) * 16;
    const int voff_ph3 = (3 * 16 + lr) * 16;

    s16x8 phB_e[4], phB_o[4];
    s16x8 greg_e, greg_o;

#define GL4(dst, off, base)                                                   \
    asm volatile("global_load_dwordx4 %0, %1, %2"                             \
                 : "=v"(dst) : "v"(off), "s"(base) : "memory")

#define LOADPH_A(dst, baseT)                                                  \
    GL4(dst[0], voff_ph0, baseT); GL4(dst[1], voff_ph1, baseT);               \
    GL4(dst[2], voff_ph2, baseT); GL4(dst[3], voff_ph3, baseT);

#define WAITVM(n) asm volatile("s_waitcnt vmcnt(" #n ")" ::: "memory")

#define QK(Sv, phB)                                                           \
    _Pragma("unroll")                                                         \
    for (int ss = 0; ss < 4; ++ss)                                            \
        Sv[ss] = __builtin_amdgcn_mfma_f32_16x16x32_bf16(thA, phB[ss], zc, 0, 0, 0);

#define EXPST(Sv, wbuf)                                                       \
    _Pragma("unroll")                                                         \
    for (int ss = 0; ss < 4; ++ss)                                            \
        _Pragma("unroll")                                                     \
        for (int r = 0; r < 4; ++r) {                                         \
            const float p = exp2f(Sv[ss][r]);                                 \
            l4[r] += p;                                                       \
            Pw[(wbuf) + (quad * 4 + r) * 72 + ss * 16 + lr] =                 \
                (unsigned short)(__float_as_uint(p) >> 16);                   \
        }

#define BODY(phCUR, phNXT, gCUR, gNXT, curT, LAST)                            \
    {                                                                         \
        WAITVM(4);   /* retire G chunk of st(curT) (oldest of 5) */           \
        __syncthreads();                                                      \
        *(s16x8*)(stg + ((curT) & 1) * 2048 + sch * 64 + swz * 8) = gCUR;     \
        if (!(LAST)) {                                                        \
            const int stn = ((curT) + 1 + stoff) & 15;                        \
            GL4(gNXT, voff_gc, gp + (size_t)stn * 64);                        \
            LOADPH_A(phNXT, ph + (size_t)stn * 512);                          \
        }                                                                     \
        const int pb = ((curT) - 1) & 1;                                      \
        const s16x8 Pf0 = *(const s16x8*)(Pw + pb * 1152 + lr * 72 + quad * 8);      \
        const s16x8 Pf1 = *(const s16x8*)(Pw + pb * 1152 + lr * 72 + 32 + quad * 8); \
        s16x8 Gf[2][2];                                                       \
        _Pragma("unroll")                                                     \
        for (int kc = 0; kc < 2; ++kc)                                        \
            _Pragma("unroll")                                                 \
            for (int cs = 0; cs < 2; ++cs)                                    \
                Gf[kc][cs] = *(const s16x8*)(stg + pb * 2048 +                \
                    (cs * 16 + lr) * 64 + ((kc * 4 + quad) ^ (lr & 7)) * 8);  \
        if (LAST) { WAITVM(0); } else { WAITVM(5); }  /* phi(st(curT)) */     \
        SB();                                                                 \
        f32x4 S[4];                                                           \
        QK(S, phCUR);                                                         \
        _Pragma("unroll")                                                     \
        for (int cs = 0; cs < 2; ++cs)                                        \
            O[cs] = __builtin_amdgcn_mfma_f32_16x16x32_bf16(Pf0, Gf[0][cs], O[cs], 0, 0, 0); \
        _Pragma("unroll")                                                     \
        for (int cs = 0; cs < 2; ++cs)                                        \
            O[cs] = __builtin_amdgcn_mfma_f32_16x16x32_bf16(Pf1, Gf[1][cs], O[cs], 0, 0, 0); \
        EXPST(S, ((curT) & 1) * 1152);                                        \
    }

    // ---- prologue: tile st(0) ----
    {
        const int st0 = stoff;
        const int st1 = (stoff + 1) & 15;
        GL4(greg_e, voff_gc, gp + (size_t)st0 * 64);
        LOADPH_A(phB_e, ph + (size_t)st0 * 512);
        WAITVM(4);                              // retire G(st0)
        *(s16x8*)(stg + 0 * 2048 + sch * 64 + swz * 8) = greg_e;
        GL4(greg_o, voff_gc, gp + (size_t)st1 * 64);
        LOADPH_A(phB_o, ph + (size_t)st1 * 512);
        WAITVM(5);                              // retire phi(st0)
        SB();
        f32x4 S[4];
        QK(S, phB_e);
        EXPST(S, 0);
    }

    // ---- steady state: t = 1..14 in ping-pong pairs ----
    for (int t = 1; t < 15; t += 2) {
        BODY(phB_o, phB_e, greg_o, greg_e, t,     0);
        BODY(phB_e, phB_o, greg_e, greg_o, t + 1, 0);
    }
    // ---- t = 15 (no next prefetch) ----
    BODY(phB_o, phB_e, greg_o, greg_e, 15, 1);

    // ---- drain: PV for tile st(15) (P in buf1, G in stage[1]) ----
    {
        __syncthreads();                        // stage[1] written by all
        const s16x8 Pf0 = *(const s16x8*)(Pw + 1152 + lr * 72 + quad * 8);
        const s16x8 Pf1 = *(const s16x8*)(Pw + 1152 + lr * 72 + 32 + quad * 8);
        s16x8 Gf[2][2];
#pragma unroll
        for (int kc = 0; kc < 2; ++kc)
#pragma unroll
            for (int cs = 0; cs < 2; ++cs)
                Gf[kc][cs] = *(const s16x8*)(stg + 2048 +
                    (cs * 16 + lr) * 64 + ((kc * 4 + quad) ^ (lr & 7)) * 8);
#pragma unroll
        for (int cs = 0; cs < 2; ++cs)
            O[cs] = __builtin_amdgcn_mfma_f32_16x16x32_bf16(Pf0, Gf[0][cs], O[cs], 0, 0, 0);
#pragma unroll
        for (int cs = 0; cs < 2; ++cs)
            O[cs] = __builtin_amdgcn_mfma_f32_16x16x32_bf16(Pf1, Gf[1][cs], O[cs], 0, 0, 0);
    }

    // l: butterfly-sum over the 16-lane s-groups
#pragma unroll
    for (int r = 0; r < 4; ++r) {
        float v = l4[r];
        v += __shfl_xor(v, 1);
        v += __shfl_xor(v, 2);
        v += __shfl_xor(v, 4);
        v += __shfl_xor(v, 8);
        l4[r] = 1.f / v;
    }

    __syncthreads();                          // all waves done with Pw/stage
    float* otile = (float*)smem;              // [32 c][68 q-stride]
#pragma unroll
    for (int cs = 0; cs < 2; ++cs) {
        f32x4 v;
#pragma unroll
        for (int r = 0; r < 4; ++r) v[r] = O[cs][r] * l4[r];
        *(f32x4*)(otile + (cs * 16 + lr) * 68 + wave * 16 + quad * 4) = v;
    }
    __syncthreads();

    // Wo epilogue + residual: thread = (q = tid&63, oc quarter = tid>>6)
    const int qq = tid & 63;
    const int quarter = __builtin_amdgcn_readfirstlane(tid >> 6);
    float ov[32];
#pragma unroll
    for (int c = 0; c < 32; ++c) ov[c] = otile[c * 68 + qq];
    const float gam = gamma_p[0];
#pragma unroll
    for (int j = 0; j < 16; ++j) {
        const float* wrow = Wo + (size_t)(quarter * 16 + j) * 32;  // contiguous
        float a = 0.f;
#pragma unroll
        for (int c = 0; c < 32; ++c) a += wrow[c] * ov[c];         // s_load
        const size_t ad = ((size_t)b * NC + quarter * 16 + j) * HWs + q0 + qq;
        out[ad] = gam * a + x[ad];
    }
}

extern "C" void kernel_launch(void* const* d_in, const int* in_sizes, int n_in,
                              void* d_out, int out_size, void* d_ws, size_t ws_size,
                              hipStream_t stream) {
    const float* x     = (const float*)d_in[0];
    const float* Wt    = (const float*)d_in[1];
    const float* Wp    = (const float*)d_in[2];
    const float* Wg    = (const float*)d_in[3];
    const float* Wo    = (const float*)d_in[4];
    const float* gamma = (const float*)d_in[5];
    float* out = (float*)d_out;
    unsigned short* ws = (unsigned short*)d_ws;

    k_proj<<<2048, 256, 0, stream>>>(x, Wt, Wp, Wg, ws);
    // attn PROBE: 2x grid, identical math, writes to ws scratch (dead data).
    // Runs after proj (needs theta/phi/gT); lands top-1 with full counters.
    k_attn_t<true><<<2048, 256, 0, stream>>>(x, Wo, gamma, ws,
                                             (float*)(ws + PROBE_OFF));
    // Real attn (overwrites every element of out).
    k_attn_t<false><<<1024, 256, 0, stream>>>(x, Wo, gamma, ws, out);
}

// Round 15
// 107.962 us; speedup vs baseline: 1.4776x; 1.4776x over previous
//
#include <hip/hip_runtime.h>
#include <math.h>

// Problem constants
#define NB   16
#define NC   64
#define HWs  4096
#define NPS  1024
#define LOG2E 1.44269504088896341f

// ws layout in ushort (bf16 bit patterns)
static constexpr size_t PHI_OFF = (size_t)NB * HWs * 8;            // theta: [b][4096][8]
static constexpr size_t GT_OFF  = PHI_OFF + (size_t)NB * NPS * 8;  // phi:   [b][1024][8]
// gT: [b][32][1024]; total 1,179,648 ushorts = 2.25 MB

typedef short s16x8 __attribute__((ext_vector_type(8)));
typedef float f32x4 __attribute__((ext_vector_type(4)));

#define LD8G(p) (*(const s16x8*)(p))
#define SB()    __builtin_amdgcn_sched_barrier(0)

__device__ inline unsigned short f2bf(float f) {
    unsigned int u = __float_as_uint(f);
    u += 0x7fffu + ((u >> 16) & 1u);          // RNE
    return (unsigned short)(u >> 16);
}
__device__ inline unsigned int pk2(float a, float b) {
    unsigned int ua = __float_as_uint(a); ua += 0x7fffu + ((ua >> 16) & 1u);
    unsigned int ub = __float_as_uint(b); ub += 0x7fffu + ((ub >> 16) & 1u);
    return (ua >> 16) | (ub & 0xffff0000u);
}

// ---------------------------------------------------------------------------
// Kernel 1 (v5): FINAL (~8-10 us, near its 32-MB-read memory floor; round-13
// probe measurement). Not touched again.
// ---------------------------------------------------------------------------
__global__ __launch_bounds__(256) __attribute__((amdgpu_waves_per_eu(8, 8)))
void k_proj(
    const float* __restrict__ x, const float* __restrict__ Wt,
    const float* __restrict__ Wp, const float* __restrict__ Wg,
    unsigned short* __restrict__ ws)
{
    __shared__ float xs[64 * 64];             // 16 KB

    unsigned short* theta = ws;
    unsigned short* phi   = ws + PHI_OFF;
    unsigned short* gT    = ws + GT_OFF;

    const int tid  = threadIdx.x;
    const int blk  = blockIdx.x;
    const int b    = blk >> 7;
    const int rp   = (blk >> 2) & 31;         // image rows {2rp, 2rp+1}
    const int half = (blk >> 1) & 1;          // block-uniform -> SGPR
    const int csub = blk & 1;                 // column half (32 cols)
    const int col0 = csub * 32;

    const float* xsrc = x + (size_t)b * NC * HWs + rp * 128;
#pragma unroll
    for (int i = 0; i < 4; ++i) {
        const int idx  = i * 256 + tid;       // 0..1023 float4 slots
        const int ci   = idx >> 4;
        const int slot = idx & 15;
        const int r    = slot >> 3;
        const int c4   = slot & 7;
        float4 v = *(const float4*)(xsrc + (size_t)ci * HWs + r * 64 + col0 + c4 * 4);
        *(float4*)(xs + ci * 64 + r * 32 + c4 * 4) = v;
    }
    __syncthreads();

    const int pxl = tid & 63;                 // r = pxl>>5, c = pxl&31
    const int r   = pxl >> 5;
    const int c   = pxl & 31;
    const int grp = __builtin_amdgcn_readfirstlane(tid >> 6);   // 0..3, SGPR

    float a2[2], ag4[4];
#pragma unroll
    for (int j = 0; j < 2; ++j) a2[j] = 0.f;
#pragma unroll
    for (int j = 0; j < 4; ++j) ag4[j] = 0.f;

    const float* W8 = (half ? Wp : Wt) + grp * 2 * NC;           // scalar base
    const float* WG = Wg + (half * 16 + grp * 4) * NC;           // scalar base

#pragma unroll 8
    for (int ci = 0; ci < NC; ++ci) {
        const float xv = xs[ci * 64 + pxl];   // 2-way bank alias: free
#pragma unroll
        for (int j = 0; j < 2; ++j) a2[j] += W8[j * NC + ci] * xv;    // s_load
#pragma unroll
        for (int j = 0; j < 4; ++j) ag4[j] += WG[j * NC + ci] * xv;   // s_load
    }

    if (half == 0) {
        const int q = (2 * rp + r) * 64 + col0 + c;
        *(unsigned int*)(theta + ((size_t)b * HWs + q) * 8 + grp * 2) =
            pk2(a2[0] * LOG2E, a2[1] * LOG2E);
    } else {
#pragma unroll
        for (int j = 0; j < 2; ++j) {
            float v = a2[j];
            v = fmaxf(v, __shfl_xor(v, 32));
            v = fmaxf(v, __shfl_xor(v, 1));
            a2[j] = v;
        }
    }

#pragma unroll
    for (int j = 0; j < 4; ++j) {
        float v = ag4[j];
        v = fmaxf(v, __shfl_xor(v, 32));
        v = fmaxf(v, __shfl_xor(v, 1));
        ag4[j] = v;
    }

    if (r == 0 && (c & 1) == 0) {
        const int ps = rp * 32 + csub * 16 + (c >> 1);
        if (half == 1) {
            *(unsigned int*)(phi + ((size_t)b * NPS + ps) * 8 + grp * 2) =
                pk2(a2[0], a2[1]);
        }
#pragma unroll
        for (int j = 0; j < 4; ++j) {
            const int ch = half * 16 + grp * 4 + j;
            gT[((size_t)b * 32 + ch) * NPS + ps] = f2bf(ag4[j]);
        }
    }
}

// ---------------------------------------------------------------------------
// Kernel 2 (v12): v11 + VALU diet. Round-19 (probe counters, first direct
// attn measurement): VALUBusy 62.8%, MfmaUtil 11.5%, Occ 33%, HBM 13% ->
// VALU is the pipe. Per-wave VALU issue ~10.8k cy = 2x the source inventory;
// prime suspect: exp2f -> __ocml_exp2_f32 denormal-safe wrapper (~3x raw
// v_exp_f32 cost) x 256/wave; second: v_lshrrev before each P ds_write_b16
// (512/wave). v12 (bit-identical math):
//  (1) __builtin_amdgcn_exp2f raw (inputs |S*log2e| <~30, far from the
//      denormal boundary; FTZ on a softmax weight is semantically fine);
//  (2) P stores via asm ds_write_b16_d16_hi (writes bits[31:16] = bf16
//      truncation for free; offsets imm from per-thread base; smem is the
//      sole __shared__ block -> LDS offset 0). Same-wave DS ops are
//      in-order, so next tile's Pf read (same wave/addr) sees the data;
//      untracked lgkm events only make compiler waits MORE conservative.
// Probe removed (instrumentation done). Everything else byte-identical.
// Predict: attn 29 -> ~22-25 us; total ~104-108.
// ---------------------------------------------------------------------------
__global__ __launch_bounds__(256) __attribute__((amdgpu_waves_per_eu(4, 4)))
void k_attn(
    const float* __restrict__ x, const float* __restrict__ Wo,
    const float* __restrict__ gamma_p, const unsigned short* __restrict__ ws,
    float* __restrict__ out)
{
    __shared__ __align__(16) unsigned char smem[26624];

    const int tid  = threadIdx.x;
    const int wave = __builtin_amdgcn_readfirstlane(tid >> 6);
    const int lane = tid & 63;
    const int quad = lane >> 4, lr = lane & 15;
    const int blk  = blockIdx.x;
    const int b    = blk >> 6;
    const int q0   = (blk & 63) * 64;
    const int stoff = blk & 15;               // tile stagger (block-uniform)

    const unsigned short* th = ws + (size_t)b * HWs * 8;
    const unsigned short* ph = ws + PHI_OFF + (size_t)b * NPS * 8;
    const unsigned short* gp = ws + GT_OFF + (size_t)b * 32 * NPS;
    unsigned short* Pw  = (unsigned short*)smem + wave * 2304;     // 2 bufs x [16 q][72 s]
    unsigned short* stg = (unsigned short*)(smem + 18432);         // 2 bufs x [32 ch][64 s]

    const int sch   = tid >> 3;
    const int spart = tid & 7;
    const int swz   = spart ^ (sch & 7);
    const int voff_gc = sch * (NPS * 2) + spart * 16;   // byte voffset into gT slab

    const s16x8 zf = {0, 0, 0, 0, 0, 0, 0, 0};
    const f32x4 zc = {0.f, 0.f, 0.f, 0.f};

    // theta A-fragment: A[m=q=lr][k=quad*8+j], real k<8 in quad 0
    const s16x8 thA = (quad == 0) ? LD8G(th + (size_t)(q0 + wave * 16 + lr) * 8) : zf;

    f32x4 O[2];
    f32x4 l4;
#pragma unroll
    for (int r = 0; r < 4; ++r) { O[0][r] = 0.f; O[1][r] = 0.f; l4[r] = 0.f; }

    const int voff_ph0 = (0 * 16 + lr) * 16;
    const int voff_ph1 = (1 * 16 + lr) * 16;
    const int voff_ph2 = (2 * 16 + lr) * 16;
    const int voff_ph3 = (3 * 16 + lr) * 16;

    s16x8 phB_e[4], phB_o[4];
    s16x8 greg_e, greg_o;

#define GL4(dst, off, base)                                                   \
    asm volatile("global_load_dwordx4 %0, %1, %2"                             \
                 : "=v"(dst) : "v"(off), "s"(base) : "memory")

#define LOADPH_A(dst, baseT)                                                  \
    GL4(dst[0], voff_ph0, baseT); GL4(dst[1], voff_ph1, baseT);               \
    GL4(dst[2], voff_ph2, baseT); GL4(dst[3], voff_ph3, baseT);

#define WAITVM(n) asm volatile("s_waitcnt vmcnt(" #n ")" ::: "memory")

#define QK(Sv, phB)                                                           \
    _Pragma("unroll")                                                         \
    for (int ss = 0; ss < 4; ++ss)                                            \
        Sv[ss] = __builtin_amdgcn_mfma_f32_16x16x32_bf16(thA, phB[ss], zc, 0, 0, 0);

// VALU-diet exp+store: raw v_exp_f32 + ds_write_b16_d16_hi (bits[31:16] =
// bf16 truncate, no shift). Offsets are compile-time immediates from a
// per-thread base; smem is the only __shared__ block (LDS offset 0).
#define EXPST(Sv, wbuf)                                                       \
    {                                                                         \
        const unsigned pb_ = (unsigned)((const char*)(Pw + (wbuf) +           \
                              (quad * 4) * 72 + lr) - (const char*)smem);     \
        _Pragma("unroll")                                                     \
        for (int ss = 0; ss < 4; ++ss)                                        \
            _Pragma("unroll")                                                 \
            for (int r = 0; r < 4; ++r) {                                     \
                const float p = __builtin_amdgcn_exp2f(Sv[ss][r]);            \
                l4[r] += p;                                                   \
                asm volatile("ds_write_b16_d16_hi %0, %1 offset:%2"           \
                             :: "v"(pb_), "v"(p), "n"(r * 144 + ss * 32)      \
                             : "memory");                                     \
            }                                                                 \
    }

#define BODY(phCUR, phNXT, gCUR, gNXT, curT, LAST)                            \
    {                                                                         \
        WAITVM(4);   /* retire G chunk of st(curT) (oldest of 5) */           \
        __syncthreads();                                                      \
        *(s16x8*)(stg + ((curT) & 1) * 2048 + sch * 64 + swz * 8) = gCUR;     \
        if (!(LAST)) {                                                        \
            const int stn = ((curT) + 1 + stoff) & 15;                        \
            GL4(gNXT, voff_gc, gp + (size_t)stn * 64);                        \
            LOADPH_A(phNXT, ph + (size_t)stn * 512);                          \
        }                                                                     \
        const int pb = ((curT) - 1) & 1;                                      \
        const s16x8 Pf0 = *(const s16x8*)(Pw + pb * 1152 + lr * 72 + quad * 8);      \
        const s16x8 Pf1 = *(const s16x8*)(Pw + pb * 1152 + lr * 72 + 32 + quad * 8); \
        s16x8 Gf[2][2];                                                       \
        _Pragma("unroll")                                                     \
        for (int kc = 0; kc < 2; ++kc)                                        \
            _Pragma("unroll")                                                 \
            for (int cs = 0; cs < 2; ++cs)                                    \
                Gf[kc][cs] = *(const s16x8*)(stg + pb * 2048 +                \
                    (cs * 16 + lr) * 64 + ((kc * 4 + quad) ^ (lr & 7)) * 8);  \
        if (LAST) { WAITVM(0); } else { WAITVM(5); }  /* phi(st(curT)) */     \
        SB();                                                                 \
        f32x4 S[4];                                                           \
        QK(S, phCUR);                                                         \
        _Pragma("unroll")                                                     \
        for (int cs = 0; cs < 2; ++cs)                                        \
            O[cs] = __builtin_amdgcn_mfma_f32_16x16x32_bf16(Pf0, Gf[0][cs], O[cs], 0, 0, 0); \
        _Pragma("unroll")                                                     \
        for (int cs = 0; cs < 2; ++cs)                                        \
            O[cs] = __builtin_amdgcn_mfma_f32_16x16x32_bf16(Pf1, Gf[1][cs], O[cs], 0, 0, 0); \
        EXPST(S, ((curT) & 1) * 1152);                                        \
    }

    // ---- prologue: tile st(0) ----
    {
        const int st0 = stoff;
        const int st1 = (stoff + 1) & 15;
        GL4(greg_e, voff_gc, gp + (size_t)st0 * 64);
        LOADPH_A(phB_e, ph + (size_t)st0 * 512);
        WAITVM(4);                              // retire G(st0)
        *(s16x8*)(stg + 0 * 2048 + sch * 64 + swz * 8) = greg_e;
        GL4(greg_o, voff_gc, gp + (size_t)st1 * 64);
        LOADPH_A(phB_o, ph + (size_t)st1 * 512);
        WAITVM(5);                              // retire phi(st0)
        SB();
        f32x4 S[4];
        QK(S, phB_e);
        EXPST(S, 0);
    }

    // ---- steady state: t = 1..14 in ping-pong pairs ----
    for (int t = 1; t < 15; t += 2) {
        BODY(phB_o, phB_e, greg_o, greg_e, t,     0);
        BODY(phB_e, phB_o, greg_e, greg_o, t + 1, 0);
    }
    // ---- t = 15 (no next prefetch) ----
    BODY(phB_o, phB_e, greg_o, greg_e, 15, 1);

    // ---- drain: PV for tile st(15) (P in buf1, G in stage[1]) ----
    {
        __syncthreads();                        // stage[1] written by all
        const s16x8 Pf0 = *(const s16x8*)(Pw + 1152 + lr * 72 + quad * 8);
        const s16x8 Pf1 = *(const s16x8*)(Pw + 1152 + lr * 72 + 32 + quad * 8);
        s16x8 Gf[2][2];
#pragma unroll
        for (int kc = 0; kc < 2; ++kc)
#pragma unroll
            for (int cs = 0; cs < 2; ++cs)
                Gf[kc][cs] = *(const s16x8*)(stg + 2048 +
                    (cs * 16 + lr) * 64 + ((kc * 4 + quad) ^ (lr & 7)) * 8);
#pragma unroll
        for (int cs = 0; cs < 2; ++cs)
            O[cs] = __builtin_amdgcn_mfma_f32_16x16x32_bf16(Pf0, Gf[0][cs], O[cs], 0, 0, 0);
#pragma unroll
        for (int cs = 0; cs < 2; ++cs)
            O[cs] = __builtin_amdgcn_mfma_f32_16x16x32_bf16(Pf1, Gf[1][cs], O[cs], 0, 0, 0);
    }

    // l: butterfly-sum over the 16-lane s-groups
#pragma unroll
    for (int r = 0; r < 4; ++r) {
        float v = l4[r];
        v += __shfl_xor(v, 1);
        v += __shfl_xor(v, 2);
        v += __shfl_xor(v, 4);
        v += __shfl_xor(v, 8);
        l4[r] = 1.f / v;
    }

    __syncthreads();                          // all waves done with Pw/stage
    float* otile = (float*)smem;              // [32 c][68 q-stride]
#pragma unroll
    for (int cs = 0; cs < 2; ++cs) {
        f32x4 v;
#pragma unroll
        for (int r = 0; r < 4; ++r) v[r] = O[cs][r] * l4[r];
        *(f32x4*)(otile + (cs * 16 + lr) * 68 + wave * 16 + quad * 4) = v;
    }
    __syncthreads();

    // Wo epilogue + residual: thread = (q = tid&63, oc quarter = tid>>6)
    const int qq = tid & 63;
    const int quarter = __builtin_amdgcn_readfirstlane(tid >> 6);
    float ov[32];
#pragma unroll
    for (int c = 0; c < 32; ++c) ov[c] = otile[c * 68 + qq];
    const float gam = gamma_p[0];
#pragma unroll
    for (int j = 0; j < 16; ++j) {
        const float* wrow = Wo + (size_t)(quarter * 16 + j) * 32;  // contiguous
        float a = 0.f;
#pragma unroll
        for (int c = 0; c < 32; ++c) a += wrow[c] * ov[c];         // s_load
        const size_t ad = ((size_t)b * NC + quarter * 16 + j) * HWs + q0 + qq;
        out[ad] = gam * a + x[ad];
    }
}

extern "C" void kernel_launch(void* const* d_in, const int* in_sizes, int n_in,
                              void* d_out, int out_size, void* d_ws, size_t ws_size,
                              hipStream_t stream) {
    const float* x     = (const float*)d_in[0];
    const float* Wt    = (const float*)d_in[1];
    const float* Wp    = (const float*)d_in[2];
    const float* Wg    = (const float*)d_in[3];
    const float* Wo    = (const float*)d_in[4];
    const float* gamma = (const float*)d_in[5];
    float* out = (float*)d_out;
    unsigned short* ws = (unsigned short*)d_ws;

    k_proj<<<2048, 256, 0, stream>>>(x, Wt, Wp, Wg, ws);
    k_attn<<<1024, 256, 0, stream>>>(x, Wo, gamma, ws, out);
}